// Round 2
// baseline (3639.197 us; speedup 1.0000x reference)
//
#include <hip/hip_runtime.h>
#include <hip/hip_bf16.h>

#define D_MODEL 1024
#define S_LEN   2048
#define BATCH   2
#define NH      16
#define HD      64

// C[M,N] = A[M,K] @ W[N,K]^T + bias[N]
// 64x64 block tile, BK=32, 256 threads, 4x4 register micro-tile. All fp32.
__global__ __launch_bounds__(256) void gemm_bias(
    const float* __restrict__ A, const float* __restrict__ W,
    const float* __restrict__ bias, float* __restrict__ C,
    int M, int N, int K)
{
    __shared__ float As[64][33];
    __shared__ float Bs[64][33];
    const int bm = blockIdx.y * 64;
    const int bn = blockIdx.x * 64;
    const int tid = threadIdx.x;
    const int tx = tid & 15, ty = tid >> 4;
    const int lr = tid >> 2;          // 0..63 load row
    const int lc = (tid & 3) * 8;     // 0,8,16,24 load col

    float acc[4][4] = {};

    for (int k0 = 0; k0 < K; k0 += 32) {
        const float* ap = A + (size_t)(bm + lr) * K + k0 + lc;
        const float* wp = W + (size_t)(bn + lr) * K + k0 + lc;
        float av[8], wv[8];
        #pragma unroll
        for (int i = 0; i < 4; ++i) { ((float2*)av)[i] = ((const float2*)ap)[i]; }
        #pragma unroll
        for (int i = 0; i < 4; ++i) { ((float2*)wv)[i] = ((const float2*)wp)[i]; }
        #pragma unroll
        for (int i = 0; i < 8; ++i) As[lr][lc + i] = av[i];
        #pragma unroll
        for (int i = 0; i < 8; ++i) Bs[lr][lc + i] = wv[i];
        __syncthreads();
        #pragma unroll
        for (int k = 0; k < 32; ++k) {
            float a[4], b[4];
            #pragma unroll
            for (int i = 0; i < 4; ++i) a[i] = As[ty * 4 + i][k];
            #pragma unroll
            for (int j = 0; j < 4; ++j) b[j] = Bs[tx * 4 + j][k];
            #pragma unroll
            for (int i = 0; i < 4; ++i)
                #pragma unroll
                for (int j = 0; j < 4; ++j) acc[i][j] += a[i] * b[j];
        }
        __syncthreads();
    }

    #pragma unroll
    for (int i = 0; i < 4; ++i) {
        const int row = bm + ty * 4 + i;
        #pragma unroll
        for (int j = 0; j < 4; ++j) {
            const int col = bn + tx * 4 + j;
            C[(size_t)row * N + col] = acc[i][j] + bias[col];
        }
    }
}

// Flash-style attention. One block = one (b, h, 64-query tile).
// Thread t: row r = t>>2, 16-wide column/dim group c16 = (t&3)*16.
// Q/K/V layout: [B][S][D_MODEL] fp32, head h occupies cols h*64..h*64+63.
__global__ __launch_bounds__(256) void attn(
    const float* __restrict__ Q, const float* __restrict__ K,
    const float* __restrict__ V, const int* __restrict__ mask,
    float* __restrict__ O)
{
    __shared__ float Qs[64][65];
    __shared__ float Ks[64][65];
    __shared__ float Vs[64][65];
    __shared__ int   msk[64];

    const int t    = threadIdx.x;
    const int qt   = blockIdx.x & 31;
    const int h    = (blockIdx.x >> 5) & 15;
    const int b    = blockIdx.x >> 9;
    const int q0   = qt * 64;
    const size_t base = (size_t)b * S_LEN * D_MODEL + (size_t)h * HD;

    const int r    = t >> 2;
    const int c16  = (t & 3) * 16;
    const int lane = t & 63;

    {
        const float* qp = Q + base + (size_t)(q0 + r) * D_MODEL + c16;
        #pragma unroll
        for (int i = 0; i < 16; ++i) Qs[r][c16 + i] = qp[i];
    }

    float m = -INFINITY, l = 0.f;
    float oa[16];
    #pragma unroll
    for (int i = 0; i < 16; ++i) oa[i] = 0.f;

    for (int kt = 0; kt < S_LEN / 64; ++kt) {
        const int k0 = kt * 64;
        __syncthreads();   // previous tile's consumers done before overwrite
        {
            const float* kp = K + base + (size_t)(k0 + r) * D_MODEL + c16;
            const float* vp = V + base + (size_t)(k0 + r) * D_MODEL + c16;
            #pragma unroll
            for (int i = 0; i < 16; ++i) Ks[r][c16 + i] = kp[i];
            #pragma unroll
            for (int i = 0; i < 16; ++i) Vs[r][c16 + i] = vp[i];
            if ((t & 3) == 0) msk[r] = mask[b * S_LEN + k0 + r];
        }
        __syncthreads();

        // scores: s[j] = Q[r,:] . K[c16+j,:]
        float sv[16];
        #pragma unroll
        for (int j = 0; j < 16; ++j) sv[j] = 0.f;
        for (int k = 0; k < 64; ++k) {
            const float qv = Qs[r][k];
            #pragma unroll
            for (int j = 0; j < 16; ++j) sv[j] += qv * Ks[c16 + j][k];
        }

        float mt = -INFINITY;
        #pragma unroll
        for (int j = 0; j < 16; ++j) {
            float s = sv[j] * 0.125f;                 // / sqrt(64)
            if (msk[c16 + j] == 0) s = -1e10f;        // NEG_INF
            sv[j] = s;
            mt = fmaxf(mt, s);
        }
        mt = fmaxf(mt, __shfl_xor(mt, 1, 64));
        mt = fmaxf(mt, __shfl_xor(mt, 2, 64));

        const float mn    = fmaxf(m, mt);
        const float alpha = (m == -INFINITY) ? 0.f : __expf(m - mn);

        float p[16];
        float ps = 0.f;
        #pragma unroll
        for (int j = 0; j < 16; ++j) { p[j] = __expf(sv[j] - mn); ps += p[j]; }
        ps += __shfl_xor(ps, 1, 64);
        ps += __shfl_xor(ps, 2, 64);

        l = l * alpha + ps;
        m = mn;
        #pragma unroll
        for (int i = 0; i < 16; ++i) oa[i] *= alpha;

        // O[r, c16+i] += sum_j p_j * V[j, c16+i]; p lives across the quad
        #pragma unroll
        for (int c2 = 0; c2 < 4; ++c2) {
            const int src = (lane & ~3) | c2;
            #pragma unroll
            for (int jj = 0; jj < 16; ++jj) {
                const float pv = __shfl(p[jj], src, 64);
                const int j = c2 * 16 + jj;
                #pragma unroll
                for (int i = 0; i < 16; ++i) oa[i] += pv * Vs[j][c16 + i];
            }
        }
    }

    const float inv = 1.f / l;
    float* op = O + base + (size_t)(q0 + r) * D_MODEL + c16;
    #pragma unroll
    for (int i = 0; i < 16; ++i) op[i] = oa[i] * inv;
}

extern "C" void kernel_launch(void* const* d_in, const int* in_sizes, int n_in,
                              void* d_out, int out_size, void* d_ws, size_t ws_size,
                              hipStream_t stream) {
    const float* x   = (const float*)d_in[0];
    const int*   mask= (const int*)  d_in[1];
    const float* Wq  = (const float*)d_in[2];
    const float* bq  = (const float*)d_in[3];
    const float* Wk  = (const float*)d_in[4];
    const float* bk  = (const float*)d_in[5];
    const float* Wv  = (const float*)d_in[6];
    const float* bv  = (const float*)d_in[7];
    const float* Wo  = (const float*)d_in[8];
    const float* bo  = (const float*)d_in[9];
    float* out = (float*)d_out;

    const int M = BATCH * S_LEN;   // 4096
    float* Qb = (float*)d_ws;                       // 16 MiB each
    float* Kb = Qb + (size_t)M * D_MODEL;
    float* Vb = Kb + (size_t)M * D_MODEL;
    float* Ob = Vb + (size_t)M * D_MODEL;           // total 64 MiB of ws

    dim3 gg(D_MODEL / 64, M / 64);                  // (16, 64)
    gemm_bias<<<gg, 256, 0, stream>>>(x, Wq, bq, Qb, M, D_MODEL, D_MODEL);
    gemm_bias<<<gg, 256, 0, stream>>>(x, Wk, bk, Kb, M, D_MODEL, D_MODEL);
    gemm_bias<<<gg, 256, 0, stream>>>(x, Wv, bv, Vb, M, D_MODEL, D_MODEL);

    attn<<<BATCH * NH * (S_LEN / 64), 256, 0, stream>>>(Qb, Kb, Vb, mask, Ob);

    gemm_bias<<<gg, 256, 0, stream>>>(Ob, Wo, bo, out, M, D_MODEL, D_MODEL);
}

// Round 3
// 331.576 us; speedup vs baseline: 10.9755x; 10.9755x over previous
//
#include <hip/hip_runtime.h>
#include <hip/hip_bf16.h>

typedef __hip_bfloat16 bf16;
typedef __attribute__((ext_vector_type(8))) short s8v;   // 8 bf16 = 4 VGPRs (MFMA A/B frag)
typedef __attribute__((ext_vector_type(4))) float f4v;   // MFMA C/D frag

#define D_MODEL 1024
#define S_LEN   2048
#define BATCH   2
#define NH      16
#define HD      64
#define M_TOTAL 4096

// ---------------- fp32 -> bf16 convert ----------------
__global__ __launch_bounds__(256) void cvt_bf16(const float* __restrict__ src,
                                                bf16* __restrict__ dst, int n) {
    int i = (blockIdx.x * 256 + threadIdx.x) * 4;
    if (i < n) {
        float4 v = *(const float4*)(src + i);
        dst[i + 0] = __float2bfloat16(v.x);
        dst[i + 1] = __float2bfloat16(v.y);
        dst[i + 2] = __float2bfloat16(v.z);
        dst[i + 3] = __float2bfloat16(v.w);
    }
}

// ---------------- MFMA GEMM: C[M,N] = A[M,K] @ W[N,K]^T + bias ----------------
// 128x128 tile, BK=32, 256 thr = 4 waves (2x2), 64x64 per wave.
// MODE 0/1: bf16 out, [b][h][s][d] layout. MODE 2: bf16 out, [b][h][d][s] (V^T).
// MODE 3: fp32 out, row-major [M][N].
template<int MODE>
__global__ __launch_bounds__(256) void gemm_mfma(
    const bf16* __restrict__ A, const bf16* __restrict__ W,
    const float* __restrict__ bias, void* __restrict__ Cout)
{
    __shared__ __align__(16) bf16 As[128][40];   // +8 pad: frag reads 2-way only
    __shared__ __align__(16) bf16 Bs[128][40];
    const int t = threadIdx.x;
    const int wv = t >> 6, lane = t & 63, quad = lane >> 4, l15 = lane & 15;
    const int wm = (wv >> 1) * 64, wn = (wv & 1) * 64;
    const int bm = blockIdx.y * 128, bn = blockIdx.x * 128;
    const int srow = t >> 1, scol = (t & 1) * 16;

    f4v acc[4][4] = {};

    for (int k0 = 0; k0 < D_MODEL; k0 += 32) {
        __syncthreads();
        const uint4* ap = (const uint4*)(A + (size_t)(bm + srow) * D_MODEL + k0 + scol);
        const uint4* wp = (const uint4*)(W + (size_t)(bn + srow) * D_MODEL + k0 + scol);
        uint4 a0 = ap[0], a1 = ap[1];
        uint4 w0 = wp[0], w1 = wp[1];
        *(uint4*)&As[srow][scol]     = a0;
        *(uint4*)&As[srow][scol + 8] = a1;
        *(uint4*)&Bs[srow][scol]     = w0;
        *(uint4*)&Bs[srow][scol + 8] = w1;
        __syncthreads();

        s8v af[4], bf_[4];
        #pragma unroll
        for (int i = 0; i < 4; ++i) af[i]  = *(const s8v*)&As[wm + i*16 + l15][quad*8];
        #pragma unroll
        for (int j = 0; j < 4; ++j) bf_[j] = *(const s8v*)&Bs[wn + j*16 + l15][quad*8];
        #pragma unroll
        for (int i = 0; i < 4; ++i)
            #pragma unroll
            for (int j = 0; j < 4; ++j)
                acc[i][j] = __builtin_amdgcn_mfma_f32_16x16x32_bf16(af[i], bf_[j], acc[i][j], 0, 0, 0);
    }

    #pragma unroll
    for (int j = 0; j < 4; ++j) {
        const int col = bn + wn + j*16 + l15;
        const float bv = bias[col];
        #pragma unroll
        for (int i = 0; i < 4; ++i) {
            #pragma unroll
            for (int r = 0; r < 4; ++r) {
                const int row = bm + wm + i*16 + quad*4 + r;
                const float v = acc[i][j][r] + bv;
                if (MODE == 3) {
                    ((float*)Cout)[(size_t)row * D_MODEL + col] = v;
                } else {
                    const int b = row >> 11, s = row & 2047, h = col >> 6, d = col & 63;
                    size_t idx;
                    if (MODE == 2) idx = (((size_t)(b*NH + h)) * HD + d) * S_LEN + s;
                    else           idx = (((size_t)(b*NH + h)) * S_LEN + s) * HD + d;
                    ((bf16*)Cout)[idx] = __float2bfloat16(v);
                }
            }
        }
    }
}

// ---------------- Flash attention, MFMA ----------------
// Q,K: [b][h][s][64] bf16.  Vt: [b][h][64][s] bf16.  O: [b][s][1024] bf16.
// Block = (b, h, 64-query tile); 4 waves, wave wv owns q rows wv*16..wv*16+15.
__global__ __launch_bounds__(256) void attn_mfma(
    const bf16* __restrict__ Q, const bf16* __restrict__ K,
    const bf16* __restrict__ Vt, const int* __restrict__ mask,
    bf16* __restrict__ O)
{
    __shared__ __align__(16) bf16 Qs[64][72];
    __shared__ __align__(16) bf16 Ks[64][72];
    __shared__ __align__(16) bf16 Vts[64][72];    // rows = d, cols = local kk
    __shared__ __align__(16) bf16 Ps[4][16][72];  // per-wave P round-trip
    __shared__ int msk[64];

    const int t = threadIdx.x;
    const int wv = t >> 6, lane = t & 63, quad = lane >> 4, l15 = lane & 15;
    const int qt = blockIdx.x & 31;
    const int h  = (blockIdx.x >> 5) & 15;
    const int b  = blockIdx.x >> 9;
    const int q0 = qt * 64;

    const size_t qkbase = ((size_t)(b*NH + h)) * S_LEN * HD;
    const size_t vtbase = ((size_t)(b*NH + h)) * HD * S_LEN;

    const int srow = t >> 2, scoff = (t & 3) * 16;

    {   // stage Q once
        const uint4* qp = (const uint4*)(Q + qkbase + (size_t)(q0 + srow) * HD + scoff);
        uint4 a = qp[0], bq = qp[1];
        *(uint4*)&Qs[srow][scoff]     = a;
        *(uint4*)&Qs[srow][scoff + 8] = bq;
    }

    float mrow[4], lrow[4];
    f4v oacc[4] = {};
    #pragma unroll
    for (int r = 0; r < 4; ++r) { mrow[r] = -1e30f; lrow[r] = 0.f; }

    for (int kt = 0; kt < S_LEN / 64; ++kt) {
        const int k0 = kt * 64;
        __syncthreads();   // previous consumers done (also fences the Q staging)
        {
            const uint4* kp = (const uint4*)(K  + qkbase + (size_t)(k0 + srow) * HD + scoff);
            const uint4* vp = (const uint4*)(Vt + vtbase + (size_t)srow * S_LEN + k0 + scoff);
            uint4 ka = kp[0], kb = kp[1];
            uint4 va = vp[0], vb = vp[1];
            *(uint4*)&Ks[srow][scoff]      = ka;
            *(uint4*)&Ks[srow][scoff + 8]  = kb;
            *(uint4*)&Vts[srow][scoff]     = va;
            *(uint4*)&Vts[srow][scoff + 8] = vb;
            if (t < 64) msk[t] = mask[b * S_LEN + k0 + t];
        }
        __syncthreads();

        // ---- S = Q K^T (16 q x 64 kk per wave) ----
        s8v qf0 = *(const s8v*)&Qs[wv*16 + l15][quad*8];
        s8v qf1 = *(const s8v*)&Qs[wv*16 + l15][32 + quad*8];
        f4v scv[4];
        #pragma unroll
        for (int c = 0; c < 4; ++c) {
            s8v kf0 = *(const s8v*)&Ks[c*16 + l15][quad*8];
            s8v kf1 = *(const s8v*)&Ks[c*16 + l15][32 + quad*8];
            f4v z = {0.f, 0.f, 0.f, 0.f};
            z = __builtin_amdgcn_mfma_f32_16x16x32_bf16(qf0, kf0, z, 0, 0, 0);
            z = __builtin_amdgcn_mfma_f32_16x16x32_bf16(qf1, kf1, z, 0, 0, 0);
            scv[c] = z;
        }

        // ---- online softmax (rows quad*4+r, cols c*16+l15) ----
        int mk[4];
        #pragma unroll
        for (int c = 0; c < 4; ++c) mk[c] = msk[c*16 + l15];

        float alpha[4];
        #pragma unroll
        for (int r = 0; r < 4; ++r) {
            float mt = -1e30f;
            #pragma unroll
            for (int c = 0; c < 4; ++c) {
                float s = scv[c][r] * 0.125f;            // 1/sqrt(64)
                if (mk[c] == 0) s = -1e10f;
                scv[c][r] = s;
                mt = fmaxf(mt, s);
            }
            mt = fmaxf(mt, __shfl_xor(mt, 1, 64));
            mt = fmaxf(mt, __shfl_xor(mt, 2, 64));
            mt = fmaxf(mt, __shfl_xor(mt, 4, 64));
            mt = fmaxf(mt, __shfl_xor(mt, 8, 64));
            const float mn = fmaxf(mrow[r], mt);
            alpha[r] = __expf(mrow[r] - mn);
            mrow[r] = mn;
            float ps = 0.f;
            #pragma unroll
            for (int c = 0; c < 4; ++c) {
                const float p = __expf(scv[c][r] - mn);
                scv[c][r] = p;
                ps += p;
            }
            ps += __shfl_xor(ps, 1, 64);
            ps += __shfl_xor(ps, 2, 64);
            ps += __shfl_xor(ps, 4, 64);
            ps += __shfl_xor(ps, 8, 64);
            lrow[r] = lrow[r] * alpha[r] + ps;
        }

        // ---- P: C-layout -> LDS -> A-layout (per-wave region, no barrier) ----
        #pragma unroll
        for (int c = 0; c < 4; ++c)
            #pragma unroll
            for (int r = 0; r < 4; ++r)
                Ps[wv][quad*4 + r][c*16 + l15] = __float2bfloat16(scv[c][r]);

        #pragma unroll
        for (int dt = 0; dt < 4; ++dt)
            #pragma unroll
            for (int r = 0; r < 4; ++r)
                oacc[dt][r] *= alpha[r];

        s8v pf0 = *(const s8v*)&Ps[wv][l15][quad*8];
        s8v pf1 = *(const s8v*)&Ps[wv][l15][32 + quad*8];
        #pragma unroll
        for (int dt = 0; dt < 4; ++dt) {
            s8v vf0 = *(const s8v*)&Vts[dt*16 + l15][quad*8];
            s8v vf1 = *(const s8v*)&Vts[dt*16 + l15][32 + quad*8];
            oacc[dt] = __builtin_amdgcn_mfma_f32_16x16x32_bf16(pf0, vf0, oacc[dt], 0, 0, 0);
            oacc[dt] = __builtin_amdgcn_mfma_f32_16x16x32_bf16(pf1, vf1, oacc[dt], 0, 0, 0);
        }
    }

    // ---- epilogue: O[b][s][h*64+d] bf16 ----
    float linv[4];
    #pragma unroll
    for (int r = 0; r < 4; ++r) linv[r] = 1.f / lrow[r];
    #pragma unroll
    for (int dt = 0; dt < 4; ++dt) {
        #pragma unroll
        for (int r = 0; r < 4; ++r) {
            const int s = q0 + wv*16 + quad*4 + r;
            const int col = h*64 + dt*16 + l15;
            O[((size_t)b * S_LEN + s) * D_MODEL + col] = __float2bfloat16(oacc[dt][r] * linv[r]);
        }
    }
}

extern "C" void kernel_launch(void* const* d_in, const int* in_sizes, int n_in,
                              void* d_out, int out_size, void* d_ws, size_t ws_size,
                              hipStream_t stream) {
    const float* x    = (const float*)d_in[0];
    const int*   mask = (const int*)  d_in[1];
    const float* Wq   = (const float*)d_in[2];
    const float* bq   = (const float*)d_in[3];
    const float* Wk   = (const float*)d_in[4];
    const float* bk   = (const float*)d_in[5];
    const float* Wv   = (const float*)d_in[6];
    const float* bv   = (const float*)d_in[7];
    const float* Wo   = (const float*)d_in[8];
    const float* bo   = (const float*)d_in[9];
    float* out = (float*)d_out;

    char* w = (char*)d_ws;
    bf16* xb  = (bf16*)w; w += (size_t)M_TOTAL * D_MODEL * 2;   // 8 MB
    bf16* Wqb = (bf16*)w; w += (size_t)D_MODEL * D_MODEL * 2;   // 2 MB
    bf16* Wkb = (bf16*)w; w += (size_t)D_MODEL * D_MODEL * 2;
    bf16* Wvb = (bf16*)w; w += (size_t)D_MODEL * D_MODEL * 2;
    bf16* Wob = (bf16*)w; w += (size_t)D_MODEL * D_MODEL * 2;
    bf16* Qb  = (bf16*)w; w += (size_t)M_TOTAL * D_MODEL * 2;   // [b][h][s][d]
    bf16* Kb  = (bf16*)w; w += (size_t)M_TOTAL * D_MODEL * 2;
    bf16* Vtb = (bf16*)w; w += (size_t)M_TOTAL * D_MODEL * 2;   // [b][h][d][s]
    bf16* Ob  = (bf16*)w; w += (size_t)M_TOTAL * D_MODEL * 2;   // [b][s][1024]

    const int nx = M_TOTAL * D_MODEL, nw = D_MODEL * D_MODEL;
    cvt_bf16<<<nx / 1024, 256, 0, stream>>>(x,  xb,  nx);
    cvt_bf16<<<nw / 1024, 256, 0, stream>>>(Wq, Wqb, nw);
    cvt_bf16<<<nw / 1024, 256, 0, stream>>>(Wk, Wkb, nw);
    cvt_bf16<<<nw / 1024, 256, 0, stream>>>(Wv, Wvb, nw);
    cvt_bf16<<<nw / 1024, 256, 0, stream>>>(Wo, Wob, nw);

    dim3 gg(D_MODEL / 128, M_TOTAL / 128);   // (8, 32)
    gemm_mfma<0><<<gg, 256, 0, stream>>>(xb, Wqb, bq, Qb);
    gemm_mfma<1><<<gg, 256, 0, stream>>>(xb, Wkb, bk, Kb);
    gemm_mfma<2><<<gg, 256, 0, stream>>>(xb, Wvb, bv, Vtb);

    attn_mfma<<<BATCH * NH * (S_LEN / 64), 256, 0, stream>>>(Qb, Kb, Vtb, mask, Ob);

    gemm_mfma<3><<<gg, 256, 0, stream>>>(Ob, Wob, bo, out);
}

// Round 4
// 240.662 us; speedup vs baseline: 15.1216x; 1.3778x over previous
//
#include <hip/hip_runtime.h>
#include <hip/hip_bf16.h>

typedef __hip_bfloat16 bf16;
typedef __attribute__((ext_vector_type(8))) short s8v;   // 8 bf16 MFMA A/B frag
typedef __attribute__((ext_vector_type(4))) float f4v;   // MFMA C/D frag

#define D_MODEL 1024
#define S_LEN   2048
#define BATCH   2
#define NH      16
#define HD      64
#define M_TOTAL 4096

// ---- async global->LDS, 16B per lane; LDS dest = uniform base + lane*16 ----
__device__ __forceinline__ void gll16(const bf16* g, bf16* l) {
    __builtin_amdgcn_global_load_lds(
        (const __attribute__((address_space(1))) void*)g,
        (__attribute__((address_space(3))) void*)l, 16, 0, 0);
}

// ---------------- fp32 -> bf16 converts ----------------
__global__ __launch_bounds__(256) void cvt_bf16x8(const float* __restrict__ s,
                                                  bf16* __restrict__ d, int n) {
    int i = (blockIdx.x * 256 + threadIdx.x) * 8;
    if (i < n) {
        float4 a = *(const float4*)(s + i);
        float4 b = *(const float4*)(s + i + 4);
        union { bf16 h[8]; uint4 u; } p;
        p.h[0] = __float2bfloat16(a.x); p.h[1] = __float2bfloat16(a.y);
        p.h[2] = __float2bfloat16(a.z); p.h[3] = __float2bfloat16(a.w);
        p.h[4] = __float2bfloat16(b.x); p.h[5] = __float2bfloat16(b.y);
        p.h[6] = __float2bfloat16(b.z); p.h[7] = __float2bfloat16(b.w);
        *(uint4*)(d + i) = p.u;
    }
}

struct WPtrs { const float* s0; const float* s1; const float* s2; const float* s3;
               bf16* d0; bf16* d1; bf16* d2; bf16* d3; };

__global__ __launch_bounds__(256) void cvt_w(WPtrs p) {
    const float* s; bf16* d;
    switch (blockIdx.y) {
        case 0:  s = p.s0; d = p.d0; break;
        case 1:  s = p.s1; d = p.d1; break;
        case 2:  s = p.s2; d = p.d2; break;
        default: s = p.s3; d = p.d3; break;
    }
    int i = (blockIdx.x * 256 + threadIdx.x) * 8;
    float4 a = *(const float4*)(s + i);
    float4 b = *(const float4*)(s + i + 4);
    union { bf16 h[8]; uint4 u; } q;
    q.h[0] = __float2bfloat16(a.x); q.h[1] = __float2bfloat16(a.y);
    q.h[2] = __float2bfloat16(a.z); q.h[3] = __float2bfloat16(a.w);
    q.h[4] = __float2bfloat16(b.x); q.h[5] = __float2bfloat16(b.y);
    q.h[6] = __float2bfloat16(b.z); q.h[7] = __float2bfloat16(b.w);
    *(uint4*)(d + i) = q.u;
}

// ---------------- GEMM main loop (m97 structure) ----------------
// C[M,N] = A[M,K=1024] @ W[N,K]^T. TMxTN tile, BK=32, 4 waves 2x2.
// LDS unpadded [rows][32] bf16 (64B rows) staged via global_load_lds w=16:
// one call = 64 lanes x 16B = 16 rows; lane l -> row l>>2, chunk l&3.
template<int TM, int TN>
__device__ __forceinline__ void gemm_main(const bf16* __restrict__ A,
                                          const bf16* __restrict__ W,
                                          bf16* As, bf16* Bs,
                                          int bm, int bn,
                                          f4v (&acc)[TM/32][TN/32])
{
    constexpr int FM = TM / 32, FN = TN / 32;
    constexpr int CALLS_A = TM / 16, CALLS = (TM + TN) / 16, PW = CALLS / 4;
    const int t = threadIdx.x, wv = t >> 6, lane = t & 63;
    const int quad = lane >> 4, l15 = lane & 15;
    const int wm = (wv >> 1) * (TM / 2), wn = (wv & 1) * (TN / 2);
    const int lr = lane >> 2, lc = (lane & 3) * 8;

    const bf16* aptr[FM];
    const bf16* bptr[FN];
    #pragma unroll
    for (int i = 0; i < FM; ++i) aptr[i] = As + (wm + i * 16 + l15) * 32 + quad * 8;
    #pragma unroll
    for (int j = 0; j < FN; ++j) bptr[j] = Bs + (wn + j * 16 + l15) * 32 + quad * 8;

    for (int k0 = 0; k0 < D_MODEL; k0 += 32) {
        __syncthreads();                       // prev frag reads done
        #pragma unroll
        for (int c = 0; c < PW; ++c) {
            const int cc = wv * PW + c;
            if (cc < CALLS_A) {
                gll16(A + (size_t)(bm + cc * 16 + lr) * D_MODEL + k0 + lc,
                      As + cc * 16 * 32);
            } else {
                const int r2 = cc - CALLS_A;
                gll16(W + (size_t)(bn + r2 * 16 + lr) * D_MODEL + k0 + lc,
                      Bs + r2 * 16 * 32);
            }
        }
        __syncthreads();                       // vmcnt(0) drain + barrier

        s8v af[FM], bfv[FN];
        #pragma unroll
        for (int i = 0; i < FM; ++i) af[i] = *(const s8v*)aptr[i];
        #pragma unroll
        for (int j = 0; j < FN; ++j) bfv[j] = *(const s8v*)bptr[j];
        #pragma unroll
        for (int i = 0; i < FM; ++i)
            #pragma unroll
            for (int j = 0; j < FN; ++j)
                acc[i][j] = __builtin_amdgcn_mfma_f32_16x16x32_bf16(af[i], bfv[j], acc[i][j], 0, 0, 0);
    }
}

// Fused QKV: grid (8, 32, 3); z=0 Q, z=1 K ([b][h][s][d]); z=2 V^T ([b][h][d][s]).
__global__ __launch_bounds__(256) void gemm_qkv(
    const bf16* __restrict__ x,
    const bf16* __restrict__ Wq, const bf16* __restrict__ Wk, const bf16* __restrict__ Wv,
    const float* __restrict__ bq, const float* __restrict__ bk, const float* __restrict__ bv,
    bf16* __restrict__ Qb, bf16* __restrict__ Kb, bf16* __restrict__ Vtb)
{
    __shared__ __align__(16) bf16 As[128 * 32];
    __shared__ __align__(16) bf16 Bs[128 * 32];
    const int z = blockIdx.z;
    const bf16*  W    = (z == 0) ? Wq : (z == 1) ? Wk : Wv;
    const float* bias = (z == 0) ? bq : (z == 1) ? bk : bv;
    bf16*        out  = (z == 0) ? Qb : (z == 1) ? Kb : Vtb;
    const int bm = blockIdx.y * 128, bn = blockIdx.x * 128;

    f4v acc[4][4] = {};
    gemm_main<128, 128>(x, W, As, Bs, bm, bn, acc);

    const int t = threadIdx.x, wv = t >> 6, lane = t & 63;
    const int quad = lane >> 4, l15 = lane & 15;
    const int wm = (wv >> 1) * 64, wn = (wv & 1) * 64;
    #pragma unroll
    for (int j = 0; j < 4; ++j) {
        const int col = bn + wn + j * 16 + l15;
        const float bv_ = bias[col];
        const int h = col >> 6, d = col & 63;
        #pragma unroll
        for (int i = 0; i < 4; ++i) {
            #pragma unroll
            for (int r = 0; r < 4; ++r) {
                const int row = bm + wm + i * 16 + quad * 4 + r;
                const int b = row >> 11, s = row & 2047;
                const float v = acc[i][j][r] + bv_;
                size_t idx;
                if (z == 2) idx = (((size_t)(b * NH + h)) * HD + d) * S_LEN + s;
                else        idx = (((size_t)(b * NH + h)) * S_LEN + s) * HD + d;
                out[idx] = __float2bfloat16(v);
            }
        }
    }
}

// Output projection: 64x128 tiles -> grid (8, 64) = 512 blocks. fp32 out.
__global__ __launch_bounds__(256) void gemm_out(
    const bf16* __restrict__ Ob, const bf16* __restrict__ Wo,
    const float* __restrict__ bo, float* __restrict__ out)
{
    __shared__ __align__(16) bf16 As[64 * 32];
    __shared__ __align__(16) bf16 Bs[128 * 32];
    const int bm = blockIdx.y * 64, bn = blockIdx.x * 128;

    f4v acc[2][4] = {};
    gemm_main<64, 128>(Ob, Wo, As, Bs, bm, bn, acc);

    const int t = threadIdx.x, wv = t >> 6, lane = t & 63;
    const int quad = lane >> 4, l15 = lane & 15;
    const int wm = (wv >> 1) * 32, wn = (wv & 1) * 64;
    #pragma unroll
    for (int j = 0; j < 4; ++j) {
        const int col = bn + wn + j * 16 + l15;
        const float bv_ = bo[col];
        #pragma unroll
        for (int i = 0; i < 2; ++i)
            #pragma unroll
            for (int r = 0; r < 4; ++r) {
                const int row = bm + wm + i * 16 + quad * 4 + r;
                out[(size_t)row * D_MODEL + col] = acc[i][j][r] + bv_;
            }
    }
}

// ---------------- Flash attention, transposed-S softmax ----------------
// S^T = K Q^T (swap MFMA args): lane (quad,l15) owns q=l15, k=c*16+quad*4+r.
// k-reduction = in-register + 2 shuffles (xor16/32). Q frags direct from global.
__global__ __launch_bounds__(256) void attn_mfma(
    const bf16* __restrict__ Q, const bf16* __restrict__ K,
    const bf16* __restrict__ Vt, const int* __restrict__ mask,
    bf16* __restrict__ O)
{
    __shared__ __align__(16) bf16 Ks[64][72];
    __shared__ __align__(16) bf16 Vts[64][72];
    __shared__ __align__(16) bf16 Ps[4][16][72];   // per-wave P round-trip [q][k]
    __shared__ __align__(16) int  msk[64];

    const int t = threadIdx.x, wv = t >> 6, lane = t & 63;
    const int quad = lane >> 4, l15 = lane & 15;
    const int qt = blockIdx.x & 31, h = (blockIdx.x >> 5) & 15, b = blockIdx.x >> 9;
    const int q0 = qt * 64;
    const size_t qkbase = ((size_t)(b * NH + h)) * S_LEN * HD;
    const size_t vtbase = ((size_t)(b * NH + h)) * HD * S_LEN;

    // Q fragments (loop-invariant), straight from global
    const bf16* qrow = Q + qkbase + (size_t)(q0 + wv * 16 + l15) * HD;
    const s8v qf0 = *(const s8v*)(qrow + quad * 8);
    const s8v qf1 = *(const s8v*)(qrow + 32 + quad * 8);

    const int srow = t >> 2, scoff = (t & 3) * 16;

    float mprev = -1e30f, lsum = 0.f;   // per-lane state for q = l15
    f4v oacc[4] = {};

    for (int kt = 0; kt < S_LEN / 64; ++kt) {
        const int k0 = kt * 64;
        __syncthreads();
        {
            const uint4* kp = (const uint4*)(K  + qkbase + (size_t)(k0 + srow) * HD + scoff);
            const uint4* vp = (const uint4*)(Vt + vtbase + (size_t)srow * S_LEN + k0 + scoff);
            uint4 ka = kp[0], kb2 = kp[1];
            uint4 va = vp[0], vb2 = vp[1];
            *(uint4*)&Ks[srow][scoff]      = ka;
            *(uint4*)&Ks[srow][scoff + 8]  = kb2;
            *(uint4*)&Vts[srow][scoff]     = va;
            *(uint4*)&Vts[srow][scoff + 8] = vb2;
            if (t < 64) msk[t] = mask[b * S_LEN + k0 + t];
        }
        __syncthreads();

        // ---- S^T tiles: rows = k-local, cols = q ----
        f4v st[4];
        #pragma unroll
        for (int c = 0; c < 4; ++c) {
            s8v kf0 = *(const s8v*)&Ks[c * 16 + l15][quad * 8];
            s8v kf1 = *(const s8v*)&Ks[c * 16 + l15][32 + quad * 8];
            f4v z = {0.f, 0.f, 0.f, 0.f};
            z = __builtin_amdgcn_mfma_f32_16x16x32_bf16(kf0, qf0, z, 0, 0, 0);
            z = __builtin_amdgcn_mfma_f32_16x16x32_bf16(kf1, qf1, z, 0, 0, 0);
            st[c] = z;
        }

        // ---- scale + mask + in-register max over this lane's 16 k ----
        float mt = -1e30f;
        #pragma unroll
        for (int c = 0; c < 4; ++c) {
            const int4 mk = *(const int4*)&msk[c * 16 + quad * 4];
            float v0 = st[c][0] * 0.125f; if (mk.x == 0) v0 = -1e10f;
            float v1 = st[c][1] * 0.125f; if (mk.y == 0) v1 = -1e10f;
            float v2 = st[c][2] * 0.125f; if (mk.z == 0) v2 = -1e10f;
            float v3 = st[c][3] * 0.125f; if (mk.w == 0) v3 = -1e10f;
            st[c][0] = v0; st[c][1] = v1; st[c][2] = v2; st[c][3] = v3;
            mt = fmaxf(mt, fmaxf(fmaxf(v0, v1), fmaxf(v2, v3)));
        }
        mt = fmaxf(mt, __shfl_xor(mt, 16, 64));   // cross-quad: full 64-k max
        mt = fmaxf(mt, __shfl_xor(mt, 32, 64));

        const float mn = fmaxf(mprev, mt);
        const float alpha = __expf(mprev - mn);
        mprev = mn;

        float ps = 0.f;
        #pragma unroll
        for (int c = 0; c < 4; ++c) {
            #pragma unroll
            for (int r = 0; r < 4; ++r) {
                const float p = __expf(st[c][r] - mn);
                st[c][r] = p;
                ps += p;
            }
        }
        ps += __shfl_xor(ps, 16, 64);
        ps += __shfl_xor(ps, 32, 64);
        lsum = lsum * alpha + ps;

        // ---- P -> LDS [q][k] (4 x b64 packed writes), per-wave region ----
        #pragma unroll
        for (int c = 0; c < 4; ++c) {
            union { bf16 h[4]; short4 s4; } pk;
            pk.h[0] = __float2bfloat16(st[c][0]);
            pk.h[1] = __float2bfloat16(st[c][1]);
            pk.h[2] = __float2bfloat16(st[c][2]);
            pk.h[3] = __float2bfloat16(st[c][3]);
            *(short4*)&Ps[wv][l15][c * 16 + quad * 4] = pk.s4;
        }

        // ---- rescale O by alpha (broadcast per output row q=quad*4+r) ----
        float av[4];
        #pragma unroll
        for (int r = 0; r < 4; ++r) av[r] = __shfl(alpha, quad * 4 + r, 64);
        #pragma unroll
        for (int dt = 0; dt < 4; ++dt)
            #pragma unroll
            for (int r = 0; r < 4; ++r) oacc[dt][r] *= av[r];

        // ---- O += P V ----
        s8v pf0 = *(const s8v*)&Ps[wv][l15][quad * 8];
        s8v pf1 = *(const s8v*)&Ps[wv][l15][32 + quad * 8];
        #pragma unroll
        for (int dt = 0; dt < 4; ++dt) {
            s8v vf0 = *(const s8v*)&Vts[dt * 16 + l15][quad * 8];
            s8v vf1 = *(const s8v*)&Vts[dt * 16 + l15][32 + quad * 8];
            oacc[dt] = __builtin_amdgcn_mfma_f32_16x16x32_bf16(pf0, vf0, oacc[dt], 0, 0, 0);
            oacc[dt] = __builtin_amdgcn_mfma_f32_16x16x32_bf16(pf1, vf1, oacc[dt], 0, 0, 0);
        }
    }

    // ---- epilogue: O[b][s][h*64+d] ----
    float linv[4];
    #pragma unroll
    for (int r = 0; r < 4; ++r) linv[r] = 1.f / __shfl(lsum, quad * 4 + r, 64);
    #pragma unroll
    for (int dt = 0; dt < 4; ++dt) {
        #pragma unroll
        for (int r = 0; r < 4; ++r) {
            const int s = q0 + wv * 16 + quad * 4 + r;
            const int col = h * 64 + dt * 16 + l15;
            O[((size_t)b * S_LEN + s) * D_MODEL + col] = __float2bfloat16(oacc[dt][r] * linv[r]);
        }
    }
}

extern "C" void kernel_launch(void* const* d_in, const int* in_sizes, int n_in,
                              void* d_out, int out_size, void* d_ws, size_t ws_size,
                              hipStream_t stream) {
    const float* x    = (const float*)d_in[0];
    const int*   mask = (const int*)  d_in[1];
    const float* Wq   = (const float*)d_in[2];
    const float* bq   = (const float*)d_in[3];
    const float* Wk   = (const float*)d_in[4];
    const float* bk   = (const float*)d_in[5];
    const float* Wv   = (const float*)d_in[6];
    const float* bv   = (const float*)d_in[7];
    const float* Wo   = (const float*)d_in[8];
    const float* bo   = (const float*)d_in[9];
    float* out = (float*)d_out;

    char* w = (char*)d_ws;
    bf16* xb  = (bf16*)w; w += (size_t)M_TOTAL * D_MODEL * 2;
    bf16* Wqb = (bf16*)w; w += (size_t)D_MODEL * D_MODEL * 2;
    bf16* Wkb = (bf16*)w; w += (size_t)D_MODEL * D_MODEL * 2;
    bf16* Wvb = (bf16*)w; w += (size_t)D_MODEL * D_MODEL * 2;
    bf16* Wob = (bf16*)w; w += (size_t)D_MODEL * D_MODEL * 2;
    bf16* Qb  = (bf16*)w; w += (size_t)M_TOTAL * D_MODEL * 2;   // [b][h][s][d]
    bf16* Kb  = (bf16*)w; w += (size_t)M_TOTAL * D_MODEL * 2;   // [b][h][s][d]
    bf16* Vtb = (bf16*)w; w += (size_t)M_TOTAL * D_MODEL * 2;   // [b][h][d][s]
    bf16* Ob  = (bf16*)w; w += (size_t)M_TOTAL * D_MODEL * 2;   // [b][s][1024]

    const int nx = M_TOTAL * D_MODEL;
    cvt_bf16x8<<<nx / 2048, 256, 0, stream>>>(x, xb, nx);
    WPtrs wp = { Wq, Wk, Wv, Wo, Wqb, Wkb, Wvb, Wob };
    cvt_w<<<dim3(D_MODEL * D_MODEL / 2048, 4), 256, 0, stream>>>(wp);

    gemm_qkv<<<dim3(8, 32, 3), 256, 0, stream>>>(xb, Wqb, Wkb, Wvb, bq, bk, bv, Qb, Kb, Vtb);

    attn_mfma<<<BATCH * NH * (S_LEN / 64), 256, 0, stream>>>(Qb, Kb, Vtb, mask, Ob);

    gemm_out<<<dim3(8, 64), 256, 0, stream>>>(Ob, Wob, bo, out);
}